// Round 4
// baseline (3452.289 us; speedup 1.0000x reference)
//
#include <hip/hip_runtime.h>
#include <cmath>

static constexpr float SCALE_ = 0.17677669529663687f; // 32^-0.5

typedef __attribute__((ext_vector_type(8))) short bf16x8;
typedef __attribute__((ext_vector_type(4))) float f32x4;

__device__ inline ushort bf16h(float f) {
    uint x = __float_as_uint(f);
    return (ushort)((x + 0x7fffu + ((x >> 16) & 1u)) >> 16);
}
__device__ inline float bf16f(ushort u) {
    return __uint_as_float(((uint)u) << 16);
}

// ---------------------------------------------------------------------------
// Small weight-combine GEMM: out[m,n] = scale * sum_k Wa[m,k]*Wb[k,n]  (f32)
// ---------------------------------------------------------------------------
__global__ __launch_bounds__(256) void smallmm_kernel(
    const float* __restrict__ Wa, const float* __restrict__ Wb,
    const float* __restrict__ scale_p, float* __restrict__ out, int NCb)
{
    int idx = blockIdx.x * 256 + threadIdx.x;
    int n4  = NCb >> 2;
    int m   = idx / n4;
    int n0  = (idx - m * n4) << 2;
    if (m >= 192) return;
    float s = scale_p[0];
    float ax = 0.f, ay = 0.f, az = 0.f, aw = 0.f;
    for (int k = 0; k < 192; ++k) {
        float a = Wa[m * 192 + k];
        const float4 b = *(const float4*)(Wb + (size_t)k * NCb + n0);
        ax += a * b.x; ay += a * b.y; az += a * b.z; aw += a * b.w;
    }
    float4 r = make_float4(ax * s, ay * s, az * s, aw * s);
    *(float4*)(out + (size_t)m * NCb + n0) = r;
}

// ---------------------------------------------------------------------------
// Activation f32 -> bf16 hi/lo planes. Rows of 9408 elems per batch; batch b
// sourced at src + b*src_bs; dest contiguous.
// ---------------------------------------------------------------------------
__global__ __launch_bounds__(256) void conv_x(
    const float* __restrict__ src, long long src_bs,
    ushort* __restrict__ dh, ushort* __restrict__ dl, long long n)
{
    long long i0 = ((long long)blockIdx.x * 256 + threadIdx.x) * 4;
    long long stride = (long long)gridDim.x * 1024;
    for (long long i = i0; i < n; i += stride) {
        long long bb = i / 9408;
        long long rem = i - bb * 9408;
        float4 v = *(const float4*)(src + bb * src_bs + rem);
        float f[4] = {v.x, v.y, v.z, v.w};
        ushort4 h4, l4;
        #pragma unroll
        for (int e = 0; e < 4; ++e) {
            ushort hh = bf16h(f[e]);
            ((ushort*)&h4)[e] = hh;
            ((ushort*)&l4)[e] = bf16h(f[e] - bf16f(hh));
        }
        *(ushort4*)(dh + i) = h4;
        *(ushort4*)(dl + i) = l4;
    }
}

// ---------------------------------------------------------------------------
// Weight f32 [192][NC] -> transposed bf16 hi/lo [NC][192]
// ---------------------------------------------------------------------------
__global__ __launch_bounds__(256) void conv_wT(
    const float* __restrict__ W, int NC,
    ushort* __restrict__ dh, ushort* __restrict__ dl)
{
    int idx = blockIdx.x * 256 + threadIdx.x;
    if (idx >= NC * 192) return;
    int nn = idx / 192, k = idx - nn * 192;
    float f = W[(long long)k * NC + nn];
    ushort hh = bf16h(f);
    dh[idx] = hh;
    dl[idx] = bf16h(f - bf16f(hh));
}

// ---------------------------------------------------------------------------
// LDS-free split-bf16 MFMA GEMM: out = A1@W1 [+ A2@W2] + bias.
// A: [M][192] bf16 hi/lo contiguous. W: transposed [NC][192] bf16 hi/lo.
// Block 128x64 (4 waves 2m x 2n, wave tile 64x32), 16x16x32 MFMA, BK=32.
// All fragments loaded directly from global (16B aligned). Zero barriers.
// F32OUT: scatter f32 to out rows (b2=m/49) else write bf16 hi/lo [M][NC].
// ---------------------------------------------------------------------------
template<bool DUAL, bool F32OUT>
__global__ __launch_bounds__(256) void gemm_bf(
    const ushort* __restrict__ Ah1, const ushort* __restrict__ Al1,
    const ushort* __restrict__ Ah2, const ushort* __restrict__ Al2,
    const ushort* __restrict__ Bh1, const ushort* __restrict__ Bl1,
    const ushort* __restrict__ Bh2, const ushort* __restrict__ Bl2,
    const float* __restrict__ bias,
    ushort* __restrict__ outH, ushort* __restrict__ outL,
    float* __restrict__ outF, long long out_bs,
    int NC, int M)
{
    const int tid = threadIdx.x;
    const int lane = tid & 63, wv = tid >> 6;
    const int wm = (wv >> 1) << 6, wn = (wv & 1) << 5;
    const int lr = lane & 15, lg = lane >> 4;
    const int bn = blockIdx.x, bm = blockIdx.y;

    int arow[4];
    #pragma unroll
    for (int i = 0; i < 4; ++i) {
        int m = bm * 128 + wm + 16 * i + lr;
        if (m >= M) m = M - 1;
        arow[i] = m * 192;
    }
    int brow[2];
    #pragma unroll
    for (int j = 0; j < 2; ++j)
        brow[j] = (bn * 64 + wn + 16 * j + lr) * 192;

    f32x4 acc[4][2] = {};
    bf16x8 a_h[2][4], a_l[2][4], b_h[2][2], b_l[2][2];
    constexpr int NS = DUAL ? 12 : 6;

    auto load = [&](int buf, int slab) {
        const ushort* AH = (!DUAL || slab < 6) ? Ah1 : Ah2;
        const ushort* AL = (!DUAL || slab < 6) ? Al1 : Al2;
        const ushort* BH = (!DUAL || slab < 6) ? Bh1 : Bh2;
        const ushort* BL = (!DUAL || slab < 6) ? Bl1 : Bl2;
        const int col = ((slab < 6) ? slab : slab - 6) * 32 + 8 * lg;
        #pragma unroll
        for (int i = 0; i < 4; ++i) {
            a_h[buf][i] = *(const bf16x8*)(AH + arow[i] + col);
            a_l[buf][i] = *(const bf16x8*)(AL + arow[i] + col);
        }
        #pragma unroll
        for (int j = 0; j < 2; ++j) {
            b_h[buf][j] = *(const bf16x8*)(BH + brow[j] + col);
            b_l[buf][j] = *(const bf16x8*)(BL + brow[j] + col);
        }
    };

    load(0, 0);
    #pragma unroll
    for (int s = 0; s < NS; ++s) {
        const int cur = s & 1;
        if (s + 1 < NS) load(cur ^ 1, s + 1);
        #pragma unroll
        for (int i = 0; i < 4; ++i)
            #pragma unroll
            for (int j = 0; j < 2; ++j) {
                acc[i][j] = __builtin_amdgcn_mfma_f32_16x16x32_bf16(a_h[cur][i], b_h[cur][j], acc[i][j], 0, 0, 0);
                acc[i][j] = __builtin_amdgcn_mfma_f32_16x16x32_bf16(a_h[cur][i], b_l[cur][j], acc[i][j], 0, 0, 0);
                acc[i][j] = __builtin_amdgcn_mfma_f32_16x16x32_bf16(a_l[cur][i], b_h[cur][j], acc[i][j], 0, 0, 0);
            }
    }

    #pragma unroll
    for (int j = 0; j < 2; ++j) {
        const int col = bn * 64 + wn + 16 * j + lr;
        const float bv = bias ? bias[col] : 0.f;
        #pragma unroll
        for (int i = 0; i < 4; ++i) {
            #pragma unroll
            for (int r = 0; r < 4; ++r) {
                const int m = bm * 128 + wm + 16 * i + 4 * lg + r;
                if (m < M) {
                    float f = acc[i][j][r] + bv;
                    if constexpr (F32OUT) {
                        int b2 = m / 49, r2 = m - b2 * 49;
                        outF[(long long)b2 * out_bs + (long long)r2 * NC + col] = f;
                    } else {
                        long long o = (long long)m * NC + col;
                        ushort hh = bf16h(f);
                        outH[o] = hh;
                        outL[o] = bf16h(f - bf16f(hh));
                    }
                }
            }
        }
    }
}

// ---------------------------------------------------------------------------
// MFMA differential attention, hi/lo bf16 inputs & outputs.
// One (batch,head) per block, 4 waves; swapped QK^T -> lane-local softmax;
// P redistribution through wave-private LDS; outputs bf16 hi/lo [M][192].
// ---------------------------------------------------------------------------
__global__ __launch_bounds__(256, 4) void attn_bf(
    const ushort* __restrict__ qTh, const ushort* __restrict__ qTl, long long qT_bs, int qT_rs,
    const ushort* __restrict__ kTh, const ushort* __restrict__ kTl, long long kT_bs, int kT_rs,
    const ushort* __restrict__ vTh, const ushort* __restrict__ vTl, long long vT_bs, int vT_rs,
    const ushort* __restrict__ qRh, const ushort* __restrict__ qRl, long long qR_bs, int qR_rs,
    const ushort* __restrict__ kRh, const ushort* __restrict__ kRl, long long kR_bs, int kR_rs,
    const ushort* __restrict__ vRh, const ushort* __restrict__ vRl, long long vR_bs, int vR_rs,
    const float* __restrict__ rpb, const float* __restrict__ lam_ptr,
    ushort* __restrict__ otH, ushort* __restrict__ otL,
    ushort* __restrict__ orH, ushort* __restrict__ orL)
{
    __shared__ __align__(16) ushort Pth[64][72];  // wave-private rows w*16..w*16+15
    __shared__ __align__(16) ushort Ptl[64][72];
    __shared__ float bias_s[169];

    const int tid = threadIdx.x;
    const int bb = blockIdx.x / 6;
    const int h  = blockIdx.x - bb * 6;
    const int hoff = h * 32;
    const int lane = tid & 63;
    const int w  = tid >> 6;
    const int li = lane & 15;
    const int lg = lane >> 4;

    for (int idx = tid; idx < 169; idx += 256) bias_s[idx] = rpb[idx * 6 + h];

    float lraw = lam_ptr[0];
    float lam = 1.f / (1.f + __expf(-lraw));
    lam = fminf(fmaxf(lam, 0.01f), 0.99f);

    const int irow = min(w * 16 + li, 48);

    // ---- scores via swapped MFMA ----
    f32x4 st[2][4];
    #pragma unroll
    for (int s = 0; s < 2; ++s) {
        const ushort* qhb = (s ? qRh : qTh) + (long long)bb * (s ? qR_bs : qT_bs) + hoff;
        const ushort* qlb = (s ? qRl : qTl) + (long long)bb * (s ? qR_bs : qT_bs) + hoff;
        const int qrs = s ? qR_rs : qT_rs;
        const ushort* khb = (s ? kRh : kTh) + (long long)bb * (s ? kR_bs : kT_bs) + hoff;
        const ushort* klb = (s ? kRl : kTl) + (long long)bb * (s ? kR_bs : kT_bs) + hoff;
        const int krs = s ? kR_rs : kT_rs;

        bf16x8 qh = *(const bf16x8*)(qhb + (long long)irow * qrs + 8 * lg);
        bf16x8 ql = *(const bf16x8*)(qlb + (long long)irow * qrs + 8 * lg);
        #pragma unroll
        for (int jt = 0; jt < 4; ++jt) {
            int jr = jt * 16 + li; if (jr > 48) jr = 48;
            bf16x8 kh = *(const bf16x8*)(khb + (long long)jr * krs + 8 * lg);
            bf16x8 kl = *(const bf16x8*)(klb + (long long)jr * krs + 8 * lg);
            f32x4 c = {};
            c = __builtin_amdgcn_mfma_f32_16x16x32_bf16(kh, qh, c, 0, 0, 0);
            c = __builtin_amdgcn_mfma_f32_16x16x32_bf16(kh, ql, c, 0, 0, 0);
            c = __builtin_amdgcn_mfma_f32_16x16x32_bf16(kl, qh, c, 0, 0, 0);
            st[s][jt] = c;
        }
    }
    __syncthreads();   // bias_s ready (only barrier)

    // ---- bias + mask + softmax (row i = w*16+li lane-local) ----
    const int ri = (irow * 9363) >> 16;
    const int ci = irow - 7 * ri;
    float bias_v[4][4];
    #pragma unroll
    for (int jt = 0; jt < 4; ++jt)
        #pragma unroll
        for (int r = 0; r < 4; ++r) {
            int j = jt * 16 + 4 * lg + r;
            int jc = (j < 49) ? j : 48;
            int rj = (jc * 9363) >> 16;
            int cj = jc - 7 * rj;
            bias_v[jt][r] = bias_s[(ri - rj + 6) * 13 + (ci - cj + 6)];
        }

    float p[2][4][4];
    #pragma unroll
    for (int s = 0; s < 2; ++s) {
        float m = -1e30f;
        #pragma unroll
        for (int jt = 0; jt < 4; ++jt)
            #pragma unroll
            for (int r = 0; r < 4; ++r) {
                int j = jt * 16 + 4 * lg + r;
                float sv = (j < 49) ? (st[s][jt][r] * SCALE_ + bias_v[jt][r]) : -1e30f;
                p[s][jt][r] = sv;
                m = fmaxf(m, sv);
            }
        m = fmaxf(m, __shfl_xor(m, 16));
        m = fmaxf(m, __shfl_xor(m, 32));
        float sum = 0.f;
        #pragma unroll
        for (int jt = 0; jt < 4; ++jt)
            #pragma unroll
            for (int r = 0; r < 4; ++r) {
                float e = __expf(p[s][jt][r] - m);
                p[s][jt][r] = e;
                sum += e;
            }
        sum += __shfl_xor(sum, 16);
        sum += __shfl_xor(sum, 32);
        float inv = 1.f / sum;
        #pragma unroll
        for (int jt = 0; jt < 4; ++jt)
            #pragma unroll
            for (int r = 0; r < 4; ++r)
                p[s][jt][r] *= inv;
    }

    // ---- PV: Peff via wave-private LDS; V hi/lo gathered from global ----
    const int prow = w * 16 + li;
    #pragma unroll
    for (int s = 0; s < 2; ++s) {
        #pragma unroll
        for (int jt = 0; jt < 4; ++jt) {
            ushort4 h4, l4;
            #pragma unroll
            for (int r = 0; r < 4; ++r) {
                float at = p[0][jt][r], ar = p[1][jt][r];
                float f = (s == 0) ? (at - lam * ar) : (ar - lam * at);
                ushort hh = bf16h(f);
                ((ushort*)&h4)[r] = hh;
                ((ushort*)&l4)[r] = bf16h(f - bf16f(hh));
            }
            *(ushort4*)&Pth[prow][jt * 16 + 4 * lg] = h4;
            *(ushort4*)&Ptl[prow][jt * 16 + 4 * lg] = l4;
        }

        const ushort* vhb = (s ? vRh : vTh) + (long long)bb * (s ? vR_bs : vT_bs) + hoff;
        const ushort* vlb = (s ? vRl : vTl) + (long long)bb * (s ? vR_bs : vT_bs) + hoff;
        const int vrs = s ? vR_rs : vT_rs;
        f32x4 acc[2] = {};
        #pragma unroll
        for (int ks = 0; ks < 2; ++ks) {
            bf16x8 pah = *(const bf16x8*)&Pth[prow][ks * 32 + 8 * lg];
            bf16x8 pal = *(const bf16x8*)&Ptl[prow][ks * 32 + 8 * lg];
            #pragma unroll
            for (int dt = 0; dt < 2; ++dt) {
                bf16x8 vh, vl;
                #pragma unroll
                for (int e = 0; e < 8; ++e) {
                    long long o = (long long)(ks * 32 + 8 * lg + e) * vrs + dt * 16 + li;
                    ((ushort*)&vh)[e] = vhb[o];
                    ((ushort*)&vl)[e] = vlb[o];
                }
                acc[dt] = __builtin_amdgcn_mfma_f32_16x16x32_bf16(pah, vh, acc[dt], 0, 0, 0);
                acc[dt] = __builtin_amdgcn_mfma_f32_16x16x32_bf16(pah, vl, acc[dt], 0, 0, 0);
                acc[dt] = __builtin_amdgcn_mfma_f32_16x16x32_bf16(pal, vh, acc[dt], 0, 0, 0);
            }
        }
        ushort* oph = s ? orH : otH;
        ushort* opl = s ? orL : otL;
        #pragma unroll
        for (int dt = 0; dt < 2; ++dt)
            #pragma unroll
            for (int r = 0; r < 4; ++r) {
                int i = w * 16 + 4 * lg + r;
                if (i < 49) {
                    long long o = ((long long)bb * 49 + i) * 192 + hoff + dt * 16 + li;
                    float f = acc[dt][r];
                    ushort hh = bf16h(f);
                    oph[o] = hh;
                    opl[o] = bf16h(f - bf16f(hh));
                }
            }
    }
}

// ---------------------------------------------------------------------------
extern "C" void kernel_launch(void* const* d_in, const int* in_sizes, int n_in,
                              void* d_out, int out_size, void* d_ws, size_t ws_size,
                              hipStream_t stream)
{
    const float* x_sa      = (const float*)d_in[0];
    const float* x_ca      = (const float*)d_in[1];
    const float* lam_sa    = (const float*)d_in[2];
    const float* lam_ca    = (const float*)d_in[3];
    const float* sa_enh    = (const float*)d_in[4];
    const float* ca_enh    = (const float*)d_in[5];
    const float* W_sa_qkv  = (const float*)d_in[6];
    const float* b_sa_qkv  = (const float*)d_in[7];
    const float* W_sa_ct   = (const float*)d_in[8];
    const float* W_sa_cr   = (const float*)d_in[9];
    const float* W_ca_q    = (const float*)d_in[10];
    const float* b_ca_q    = (const float*)d_in[11];
    const float* W_ca_kv   = (const float*)d_in[12];
    const float* b_ca_kv   = (const float*)d_in[13];
    const float* W_ca_ct   = (const float*)d_in[14];
    const float* W_ca_cr   = (const float*)d_in[15];
    const float* rpb       = (const float*)d_in[16];
    const float* W_proj_sa = (const float*)d_in[17];
    const float* b_proj_sa = (const float*)d_in[18];
    const float* W_proj_ca = (const float*)d_in[19];
    const float* b_proj_ca = (const float*)d_in[20];
    float* out = (float*)d_out;
    float* ws  = (float*)d_ws;

    // ---- f32 combined-weight temps ----
    float* CW0 = ws;             // 192x576
    float* CW1 = CW0 + 110592;
    float* CW2 = CW1 + 110592;   // 192x192
    float* CW3 = CW2 + 36864;
    float* CW4 = CW3 + 36864;    // 192x384
    float* CW5 = CW4 + 73728;

    smallmm_kernel<<<108, 256, 0, stream>>>(W_sa_cr, W_sa_qkv, sa_enh, CW0, 576);
    smallmm_kernel<<<108, 256, 0, stream>>>(W_sa_ct, W_sa_qkv, sa_enh, CW1, 576);
    smallmm_kernel<<< 36, 256, 0, stream>>>(W_ca_cr, W_ca_q,   ca_enh, CW2, 192);
    smallmm_kernel<<< 36, 256, 0, stream>>>(W_ca_ct, W_ca_q,   ca_enh, CW3, 192);
    smallmm_kernel<<< 72, 256, 0, stream>>>(W_ca_cr, W_ca_kv,  ca_enh, CW4, 384);
    smallmm_kernel<<< 72, 256, 0, stream>>>(W_ca_ct, W_ca_kv,  ca_enh, CW5, 384);

    // ---- bf16 hi/lo transposed weight area ----
    ushort* wb = (ushort*)(ws + 442368);
    ushort* WsaqH = wb;                  ushort* WsaqL = WsaqH + 110592;
    ushort* C0H  = WsaqL + 110592;       ushort* C0L  = C0H + 110592;
    ushort* C1H  = C0L + 110592;         ushort* C1L  = C1H + 110592;
    ushort* WcqH = C1L + 110592;         ushort* WcqL = WcqH + 36864;
    ushort* C2H  = WcqL + 36864;         ushort* C2L  = C2H + 36864;
    ushort* C3H  = C2L + 36864;          ushort* C3L  = C3H + 36864;
    ushort* WckH = C3L + 36864;          ushort* WckL = WckH + 73728;
    ushort* C4H  = WckL + 73728;         ushort* C4L  = C4H + 73728;
    ushort* C5H  = C4L + 73728;          ushort* C5L  = C5H + 73728;
    ushort* WpsH = C5L + 73728;          ushort* WpsL = WpsH + 36864;
    ushort* WpcH = WpsL + 36864;         ushort* WpcL = WpcH + 36864;
    ushort* chunkU = WpcL + 36864;       // = wb + 1474560

    conv_wT<<<432, 256, 0, stream>>>(W_sa_qkv, 576, WsaqH, WsaqL);
    conv_wT<<<432, 256, 0, stream>>>(CW0,      576, C0H,  C0L);
    conv_wT<<<432, 256, 0, stream>>>(CW1,      576, C1H,  C1L);
    conv_wT<<<144, 256, 0, stream>>>(W_ca_q,   192, WcqH, WcqL);
    conv_wT<<<144, 256, 0, stream>>>(CW2,      192, C2H,  C2L);
    conv_wT<<<144, 256, 0, stream>>>(CW3,      192, C3H,  C3L);
    conv_wT<<<288, 256, 0, stream>>>(W_ca_kv,  384, WckH, WckL);
    conv_wT<<<288, 256, 0, stream>>>(CW4,      384, C4H,  C4L);
    conv_wT<<<288, 256, 0, stream>>>(CW5,      384, C5H,  C5L);
    conv_wT<<<144, 256, 0, stream>>>(W_proj_sa,192, WpsH, WpsL);
    conv_wT<<<144, 256, 0, stream>>>(W_proj_ca,192, WpcH, WpcL);

    // ---- chunking: 376320 bytes per batch element ----
    long long avail = (long long)ws_size - 442368LL * 4 - 1474560LL * 2;
    int cbmax = (int)(avail / 376320);
    if (cbmax > 2048) cbmax = 2048;
    if (cbmax < 1) cbmax = 1;

    const long long OUT1 = 2LL * 2048 * 49 * 192;
    dim3 blk(256);

    for (int c0 = 0; c0 < 2048; c0 += cbmax) {
        int cb = (c0 + cbmax <= 2048) ? cbmax : (2048 - c0);
        int M = cb * 49;
        int gy = (M + 127) / 128;
        long long nconv = (long long)cb * 9408;
        int cblk = (int)(((nconv / 4) + 255) / 256);
        if (cblk > 8192) cblk = 8192;

        // =========================== SA branch ===========================
        ushort* XaH = chunkU;                             // [2][cb*49][192]
        ushort* XaL = XaH + (long long)cbmax * 18816;
        ushort* QtH = XaL + (long long)cbmax * 18816;     // qkv_t [M][576]
        ushort* QtL = QtH + (long long)cbmax * 28224;
        ushort* QrH = QtL + (long long)cbmax * 28224;
        ushort* QrL = QrH + (long long)cbmax * 28224;
        ushort* OtH = QrL + (long long)cbmax * 28224;     // [M][192]
        ushort* OtL = OtH + (long long)cbmax * 9408;
        ushort* OrH = OtL + (long long)cbmax * 9408;
        ushort* OrL = OrH + (long long)cbmax * 9408;

        conv_x<<<cblk, blk, 0, stream>>>(x_sa + (long long)c0 * 9408, 9408,
                                         XaH, XaL, nconv);
        conv_x<<<cblk, blk, 0, stream>>>(x_sa + (2048LL + c0) * 9408, 9408,
                                         XaH + (long long)cbmax * 9408,
                                         XaL + (long long)cbmax * 9408, nconv);

        ushort* XrH = XaH + (long long)cbmax * 9408;
        ushort* XrL = XaL + (long long)cbmax * 9408;

        dim3 g1(9, gy);
        gemm_bf<true, false><<<g1, blk, 0, stream>>>(
            XaH, XaL, XrH, XrL, WsaqH, WsaqL, C0H, C0L,
            b_sa_qkv, QtH, QtL, nullptr, 0, 576, M);
        gemm_bf<true, false><<<g1, blk, 0, stream>>>(
            XrH, XrL, XaH, XaL, WsaqH, WsaqL, C1H, C1L,
            b_sa_qkv, QrH, QrL, nullptr, 0, 576, M);

        attn_bf<<<cb * 6, blk, 0, stream>>>(
            QtH,       QtL,       28224, 576,
            QtH + 192, QtL + 192, 28224, 576,
            QtH + 384, QtL + 384, 28224, 576,
            QrH,       QrL,       28224, 576,
            QrH + 192, QrL + 192, 28224, 576,
            QrH + 384, QrL + 384, 28224, 576,
            rpb, lam_sa, OtH, OtL, OrH, OrL);

        dim3 g2(3, gy);
        gemm_bf<false, true><<<g2, blk, 0, stream>>>(
            OtH, OtL, nullptr, nullptr, WpsH, WpsL, nullptr, nullptr,
            b_proj_sa, nullptr, nullptr, out + (long long)c0 * 9408, 9408, 192, M);
        gemm_bf<false, true><<<g2, blk, 0, stream>>>(
            OrH, OrL, nullptr, nullptr, WpsH, WpsL, nullptr, nullptr,
            b_proj_sa, nullptr, nullptr, out + (2048LL + c0) * 9408, 9408, 192, M);

        // =========================== CA branch ===========================
        ushort* XtH = chunkU;                             // te [M][192]
        ushort* XtL = XtH + (long long)cbmax * 9408;
        ushort* XcrH = XtL + (long long)cbmax * 9408;     // re [M][192]
        ushort* XcrL = XcrH + (long long)cbmax * 9408;
        ushort* CQtH = XcrL + (long long)cbmax * 9408;    // q_t [M][192]
        ushort* CQtL = CQtH + (long long)cbmax * 9408;
        ushort* CQrH = CQtL + (long long)cbmax * 9408;
        ushort* CQrL = CQrH + (long long)cbmax * 9408;
        ushort* KtH = CQrL + (long long)cbmax * 9408;     // kv_t [M][384]
        ushort* KtL = KtH + (long long)cbmax * 18816;
        ushort* KrH = KtL + (long long)cbmax * 18816;
        ushort* KrL = KrH + (long long)cbmax * 18816;
        ushort* COtH = KrL + (long long)cbmax * 18816;    // [M][192]
        ushort* COtL = COtH + (long long)cbmax * 9408;
        ushort* COrH = COtL + (long long)cbmax * 9408;
        ushort* COrL = COrH + (long long)cbmax * 9408;

        conv_x<<<cblk, blk, 0, stream>>>(x_ca + (long long)c0 * 18816, 18816,
                                         XtH, XtL, nconv);
        conv_x<<<cblk, blk, 0, stream>>>(x_ca + (long long)c0 * 18816 + 9408, 18816,
                                         XcrH, XcrL, nconv);

        gemm_bf<true, false><<<g2, blk, 0, stream>>>(
            XtH, XtL, XcrH, XcrL, WcqH, WcqL, C2H, C2L,
            b_ca_q, CQtH, CQtL, nullptr, 0, 192, M);
        gemm_bf<true, false><<<g2, blk, 0, stream>>>(
            XcrH, XcrL, XtH, XtL, WcqH, WcqL, C3H, C3L,
            b_ca_q, CQrH, CQrL, nullptr, 0, 192, M);

        dim3 g3(6, gy);
        gemm_bf<true, false><<<g3, blk, 0, stream>>>(
            XtH, XtL, XcrH, XcrL, WckH, WckL, C4H, C4L,
            b_ca_kv, KtH, KtL, nullptr, 0, 384, M);
        gemm_bf<true, false><<<g3, blk, 0, stream>>>(
            XcrH, XcrL, XtH, XtL, WckH, WckL, C5H, C5L,
            b_ca_kv, KrH, KrL, nullptr, 0, 384, M);

        attn_bf<<<cb * 6, blk, 0, stream>>>(
            CQtH,      CQtL,      9408, 192,
            KtH,       KtL,       18816, 384,
            KtH + 192, KtL + 192, 18816, 384,
            CQrH,      CQrL,      9408, 192,
            KrH,       KrL,       18816, 384,
            KrH + 192, KrL + 192, 18816, 384,
            rpb, lam_ca, COtH, COtL, COrH, COrL);

        gemm_bf<false, true><<<g2, blk, 0, stream>>>(
            COtH, COtL, nullptr, nullptr, WpcH, WpcL, nullptr, nullptr,
            b_proj_ca, nullptr, nullptr,
            out + OUT1 + (long long)c0 * 18816, 18816, 192, M);
        gemm_bf<false, true><<<g2, blk, 0, stream>>>(
            COrH, COrL, nullptr, nullptr, WpcH, WpcL, nullptr, nullptr,
            b_proj_ca, nullptr, nullptr,
            out + OUT1 + (long long)c0 * 18816 + 9408, 18816, 192, M);
    }
}

// Round 5
// 1753.021 us; speedup vs baseline: 1.9693x; 1.9693x over previous
//
#include <hip/hip_runtime.h>
#include <cmath>

static constexpr float SCALE_ = 0.17677669529663687f; // 32^-0.5

typedef __attribute__((ext_vector_type(8))) short bf16x8;
typedef __attribute__((ext_vector_type(8))) ushort u16x8;
typedef __attribute__((ext_vector_type(4))) float f32x4;

__device__ inline ushort bf16h(float f) {
    uint x = __float_as_uint(f);
    return (ushort)((x + 0x7fffu + ((x >> 16) & 1u)) >> 16);
}
__device__ inline float bf16f(ushort u) {
    return __uint_as_float(((uint)u) << 16);
}

// ---------------------------------------------------------------------------
// Small weight-combine GEMM (f32): out[m,n] = scale * sum_k Wa[m,k]*Wb[k,n]
// ---------------------------------------------------------------------------
__global__ __launch_bounds__(256) void smallmm_kernel(
    const float* __restrict__ Wa, const float* __restrict__ Wb,
    const float* __restrict__ scale_p, float* __restrict__ out, int NCb)
{
    int idx = blockIdx.x * 256 + threadIdx.x;
    int n4  = NCb >> 2;
    int m   = idx / n4;
    int n0  = (idx - m * n4) << 2;
    if (m >= 192) return;
    float s = scale_p[0];
    float ax = 0.f, ay = 0.f, az = 0.f, aw = 0.f;
    for (int k = 0; k < 192; ++k) {
        float a = Wa[m * 192 + k];
        const float4 b = *(const float4*)(Wb + (size_t)k * NCb + n0);
        ax += a * b.x; ay += a * b.y; az += a * b.z; aw += a * b.w;
    }
    float4 r = make_float4(ax * s, ay * s, az * s, aw * s);
    *(float4*)(out + (size_t)m * NCb + n0) = r;
}

// ---------------------------------------------------------------------------
// Activation f32 [rows of 192 at (bb,src_bs)] -> K-slabbed bf16 hi/lo
// [6][Mc][32]. Mc = cb*49.
// ---------------------------------------------------------------------------
__global__ __launch_bounds__(256) void conv_x(
    const float* __restrict__ src, long long src_bs,
    ushort* __restrict__ dh, ushort* __restrict__ dl, int Mc)
{
    const long long SS = (long long)Mc * 32;
    const long long total8 = (long long)Mc * 24;
    for (long long t = (long long)blockIdx.x * 256 + threadIdx.x; t < total8;
         t += (long long)gridDim.x * 256) {
        int m  = (int)(t / 24);
        int c8 = (int)(t - (long long)m * 24) * 8;
        int bb = m / 49, r = m - bb * 49;
        const float* sp = src + (long long)bb * src_bs + r * 192 + c8;
        float4 v0 = *(const float4*)sp;
        float4 v1 = *(const float4*)(sp + 4);
        float f[8] = {v0.x, v0.y, v0.z, v0.w, v1.x, v1.y, v1.z, v1.w};
        u16x8 h8, l8;
        #pragma unroll
        for (int e = 0; e < 8; ++e) {
            ushort hh = bf16h(f[e]);
            h8[e] = hh;
            l8[e] = bf16h(f[e] - bf16f(hh));
        }
        long long o = (long long)(c8 >> 5) * SS + (long long)m * 32 + (c8 & 31);
        *(u16x8*)(dh + o) = h8;
        *(u16x8*)(dl + o) = l8;
    }
}

// ---------------------------------------------------------------------------
// Weight f32 [192][NC] -> K-slabbed transposed bf16 hi/lo [6][NC][32]
// ---------------------------------------------------------------------------
__global__ __launch_bounds__(256) void conv_wT(
    const float* __restrict__ W, int NC,
    ushort* __restrict__ dh, ushort* __restrict__ dl)
{
    int idx = blockIdx.x * 256 + threadIdx.x;
    if (idx >= NC * 192) return;
    int n = idx / 192, k = idx - n * 192;
    float f = W[(long long)k * NC + n];
    long long o = ((long long)(k >> 5) * NC + n) * 32 + (k & 31);
    ushort hh = bf16h(f);
    dh[o] = hh;
    dl[o] = bf16h(f - bf16f(hh));
}

// ---------------------------------------------------------------------------
// Split-bf16 MFMA GEMM on pre-converted K-slabbed planes.
// A: [6][M][32] hi/lo per operand. W: [6][NC][32] hi/lo.
// Block tile 128M x 192N, 4 waves (2m x 2n), wave 64x96, 16x16x32 MFMA.
// A staged in LDS (prefetched 1 slab ahead); B frags direct from L2.
// F32OUT: scatter f32 (b2=m/49, row stride 192); else slabbed hi/lo out.
// ---------------------------------------------------------------------------
template<bool DUAL, bool F32OUT>
__global__ __launch_bounds__(256, 2) void gemm_slab(
    const ushort* __restrict__ Ah1, const ushort* __restrict__ Al1,
    const ushort* __restrict__ Ah2, const ushort* __restrict__ Al2,
    const ushort* __restrict__ Bh1, const ushort* __restrict__ Bl1,
    const ushort* __restrict__ Bh2, const ushort* __restrict__ Bl2,
    const float* __restrict__ bias,
    ushort* __restrict__ outH, ushort* __restrict__ outL,
    float* __restrict__ outF, long long out_bs,
    int NC, int M)
{
    __shared__ __align__(16) ushort Ash[128][36];
    __shared__ __align__(16) ushort Asl[128][36];

    const int tid = threadIdx.x;
    const int lane = tid & 63, wv = tid >> 6;
    const int wm = (wv >> 1) * 64, wn = (wv & 1) * 96;
    const int lr = lane & 15, lg = lane >> 4;
    const int bn = blockIdx.x, bm = blockIdx.y;
    const int n0 = bn * 192;
    const long long SS = (long long)M * 32;

    int arow = bm * 128 + (tid >> 1); if (arow >= M) arow = M - 1;
    const int th16 = (tid & 1) * 16;
    const long long aoff = (long long)arow * 32 + th16;
    const int srow = tid >> 1;

    int brow[6];
    #pragma unroll
    for (int j = 0; j < 6; ++j) brow[j] = (n0 + wn + 16 * j + lr) * 32 + 8 * lg;

    f32x4 acc[4][6] = {};
    constexpr int NS = DUAL ? 12 : 6;

    bf16x8 gh0, gh1, gl0, gl1;
    gh0 = *(const bf16x8*)(Ah1 + aoff);
    gh1 = *(const bf16x8*)(Ah1 + aoff + 8);
    gl0 = *(const bf16x8*)(Al1 + aoff);
    gl1 = *(const bf16x8*)(Al1 + aoff + 8);

    for (int s = 0; s < NS; ++s) {
        const int k6 = (s < 6) ? s : s - 6;
        const ushort* BH = (!DUAL || s < 6) ? Bh1 : Bh2;
        const ushort* BL = (!DUAL || s < 6) ? Bl1 : Bl2;
        const long long sb = (long long)k6 * NC * 32;
        bf16x8 bh[6], bl[6];
        #pragma unroll
        for (int j = 0; j < 6; ++j) {
            bh[j] = *(const bf16x8*)(BH + sb + brow[j]);
            bl[j] = *(const bf16x8*)(BL + sb + brow[j]);
        }

        __syncthreads();   // prior slab's frag reads done
        *(bf16x8*)&Ash[srow][th16]     = gh0;
        *(bf16x8*)&Ash[srow][th16 + 8] = gh1;
        *(bf16x8*)&Asl[srow][th16]     = gl0;
        *(bf16x8*)&Asl[srow][th16 + 8] = gl1;
        if (s + 1 < NS) {
            const ushort* AH = (!DUAL || s + 1 < 6) ? Ah1 : Ah2;
            const ushort* AL = (!DUAL || s + 1 < 6) ? Al1 : Al2;
            const long long o2 = (long long)((s + 1 < 6) ? (s + 1) : (s - 5)) * SS + aoff;
            gh0 = *(const bf16x8*)(AH + o2);
            gh1 = *(const bf16x8*)(AH + o2 + 8);
            gl0 = *(const bf16x8*)(AL + o2);
            gl1 = *(const bf16x8*)(AL + o2 + 8);
        }
        __syncthreads();   // slab s visible

        bf16x8 ah[4], al[4];
        #pragma unroll
        for (int i = 0; i < 4; ++i) {
            ah[i] = *(const bf16x8*)&Ash[wm + 16 * i + lr][8 * lg];
            al[i] = *(const bf16x8*)&Asl[wm + 16 * i + lr][8 * lg];
        }
        #pragma unroll
        for (int i = 0; i < 4; ++i)
            #pragma unroll
            for (int j = 0; j < 6; ++j) {
                acc[i][j] = __builtin_amdgcn_mfma_f32_16x16x32_bf16(ah[i], bh[j], acc[i][j], 0, 0, 0);
                acc[i][j] = __builtin_amdgcn_mfma_f32_16x16x32_bf16(ah[i], bl[j], acc[i][j], 0, 0, 0);
                acc[i][j] = __builtin_amdgcn_mfma_f32_16x16x32_bf16(al[i], bh[j], acc[i][j], 0, 0, 0);
            }
    }

    #pragma unroll
    for (int j = 0; j < 6; ++j) {
        const int c = n0 + wn + 16 * j + lr;
        const float bv = bias ? bias[c] : 0.f;
        const long long obase = (long long)(c >> 5) * SS + (c & 31);
        #pragma unroll
        for (int i = 0; i < 4; ++i)
            #pragma unroll
            for (int r = 0; r < 4; ++r) {
                int m = bm * 128 + wm + 16 * i + 4 * lg + r;
                if (m < M) {
                    float f = acc[i][j][r] + bv;
                    if constexpr (F32OUT) {
                        int b2 = m / 49, r2 = m - b2 * 49;
                        outF[(long long)b2 * out_bs + r2 * 192 + c] = f;
                    } else {
                        long long o = obase + (long long)m * 32;
                        ushort hh = bf16h(f);
                        outH[o] = hh;
                        outL[o] = bf16h(f - bf16f(hh));
                    }
                }
            }
    }
}

// ---------------------------------------------------------------------------
// MFMA differential attention on K-slabbed hi/lo planes.
// q/k/v base pointers pre-offset so head h lives at base + h*SS.
// One (batch,head) per block, 4 waves; swapped QK^T; wave-private P LDS.
// Outputs slabbed [6][Mc][32] hi/lo.
// ---------------------------------------------------------------------------
__global__ __launch_bounds__(256, 4) void attn_bf(
    const ushort* __restrict__ qTh, const ushort* __restrict__ qTl,
    const ushort* __restrict__ kTh, const ushort* __restrict__ kTl,
    const ushort* __restrict__ vTh, const ushort* __restrict__ vTl,
    const ushort* __restrict__ qRh, const ushort* __restrict__ qRl,
    const ushort* __restrict__ kRh, const ushort* __restrict__ kRl,
    const ushort* __restrict__ vRh, const ushort* __restrict__ vRl,
    long long SS,
    const float* __restrict__ rpb, const float* __restrict__ lam_ptr,
    ushort* __restrict__ otH, ushort* __restrict__ otL,
    ushort* __restrict__ orH, ushort* __restrict__ orL)
{
    __shared__ __align__(16) ushort Pth[64][72];
    __shared__ __align__(16) ushort Ptl[64][72];
    __shared__ float bias_s[169];

    const int tid = threadIdx.x;
    const int bb = blockIdx.x / 6;
    const int h  = blockIdx.x - bb * 6;
    const int lane = tid & 63;
    const int w  = tid >> 6;
    const int li = lane & 15;
    const int lg = lane >> 4;
    const long long rowbase = (long long)bb * 49 * 32;
    const long long hb = (long long)h * SS + rowbase;

    for (int idx = tid; idx < 169; idx += 256) bias_s[idx] = rpb[idx * 6 + h];

    float lraw = lam_ptr[0];
    float lam = 1.f / (1.f + __expf(-lraw));
    lam = fminf(fmaxf(lam, 0.01f), 0.99f);

    const int irow = min(w * 16 + li, 48);

    // ---- scores via swapped MFMA ----
    f32x4 st[2][4];
    #pragma unroll
    for (int s = 0; s < 2; ++s) {
        const ushort* qhb = (s ? qRh : qTh) + hb;
        const ushort* qlb = (s ? qRl : qTl) + hb;
        const ushort* khb = (s ? kRh : kTh) + hb;
        const ushort* klb = (s ? kRl : kTl) + hb;

        bf16x8 qh = *(const bf16x8*)(qhb + irow * 32 + 8 * lg);
        bf16x8 ql = *(const bf16x8*)(qlb + irow * 32 + 8 * lg);
        #pragma unroll
        for (int jt = 0; jt < 4; ++jt) {
            int jr = jt * 16 + li; if (jr > 48) jr = 48;
            bf16x8 kh = *(const bf16x8*)(khb + jr * 32 + 8 * lg);
            bf16x8 kl = *(const bf16x8*)(klb + jr * 32 + 8 * lg);
            f32x4 c = {};
            c = __builtin_amdgcn_mfma_f32_16x16x32_bf16(kh, qh, c, 0, 0, 0);
            c = __builtin_amdgcn_mfma_f32_16x16x32_bf16(kh, ql, c, 0, 0, 0);
            c = __builtin_amdgcn_mfma_f32_16x16x32_bf16(kl, qh, c, 0, 0, 0);
            st[s][jt] = c;
        }
    }
    __syncthreads();   // bias_s ready (only barrier)

    // ---- bias + mask + softmax (row i = w*16+li lane-local) ----
    const int ri = (irow * 9363) >> 16;
    const int ci = irow - 7 * ri;
    float bias_v[4][4];
    #pragma unroll
    for (int jt = 0; jt < 4; ++jt)
        #pragma unroll
        for (int r = 0; r < 4; ++r) {
            int j = jt * 16 + 4 * lg + r;
            int jc = (j < 49) ? j : 48;
            int rj = (jc * 9363) >> 16;
            int cj = jc - 7 * rj;
            bias_v[jt][r] = bias_s[(ri - rj + 6) * 13 + (ci - cj + 6)];
        }

    float p[2][4][4];
    #pragma unroll
    for (int s = 0; s < 2; ++s) {
        float m = -1e30f;
        #pragma unroll
        for (int jt = 0; jt < 4; ++jt)
            #pragma unroll
            for (int r = 0; r < 4; ++r) {
                int j = jt * 16 + 4 * lg + r;
                float sv = (j < 49) ? (st[s][jt][r] * SCALE_ + bias_v[jt][r]) : -1e30f;
                p[s][jt][r] = sv;
                m = fmaxf(m, sv);
            }
        m = fmaxf(m, __shfl_xor(m, 16));
        m = fmaxf(m, __shfl_xor(m, 32));
        float sum = 0.f;
        #pragma unroll
        for (int jt = 0; jt < 4; ++jt)
            #pragma unroll
            for (int r = 0; r < 4; ++r) {
                float e = __expf(p[s][jt][r] - m);
                p[s][jt][r] = e;
                sum += e;
            }
        sum += __shfl_xor(sum, 16);
        sum += __shfl_xor(sum, 32);
        float inv = 1.f / sum;
        #pragma unroll
        for (int jt = 0; jt < 4; ++jt)
            #pragma unroll
            for (int r = 0; r < 4; ++r)
                p[s][jt][r] *= inv;
    }

    // ---- PV: Peff via wave-private LDS; V hi/lo gathered from global ----
    const int prow = w * 16 + li;
    #pragma unroll
    for (int s = 0; s < 2; ++s) {
        #pragma unroll
        for (int jt = 0; jt < 4; ++jt) {
            ushort4 h4, l4;
            #pragma unroll
            for (int r = 0; r < 4; ++r) {
                float at = p[0][jt][r], ar = p[1][jt][r];
                float f = (s == 0) ? (at - lam * ar) : (ar - lam * at);
                ushort hh = bf16h(f);
                ((ushort*)&h4)[r] = hh;
                ((ushort*)&l4)[r] = bf16h(f - bf16f(hh));
            }
            *(ushort4*)&Pth[prow][jt * 16 + 4 * lg] = h4;
            *(ushort4*)&Ptl[prow][jt * 16 + 4 * lg] = l4;
        }

        const ushort* vhb = (s ? vRh : vTh) + hb;
        const ushort* vlb = (s ? vRl : vTl) + hb;
        f32x4 acc[2] = {};
        #pragma unroll
        for (int ks = 0; ks < 2; ++ks) {
            bf16x8 pah = *(const bf16x8*)&Pth[prow][ks * 32 + 8 * lg];
            bf16x8 pal = *(const bf16x8*)&Ptl[prow][ks * 32 + 8 * lg];
            #pragma unroll
            for (int dt = 0; dt < 2; ++dt) {
                bf16x8 vh, vl;
                #pragma unroll
                for (int e = 0; e < 8; ++e) {
                    long long o = (long long)(ks * 32 + 8 * lg + e) * 32 + dt * 16 + li;
                    vh[e] = (short)vhb[o];
                    vl[e] = (short)vlb[o];
                }
                acc[dt] = __builtin_amdgcn_mfma_f32_16x16x32_bf16(pah, vh, acc[dt], 0, 0, 0);
                acc[dt] = __builtin_amdgcn_mfma_f32_16x16x32_bf16(pah, vl, acc[dt], 0, 0, 0);
                acc[dt] = __builtin_amdgcn_mfma_f32_16x16x32_bf16(pal, vh, acc[dt], 0, 0, 0);
            }
        }
        ushort* oph = s ? orH : otH;
        ushort* opl = s ? orL : otL;
        #pragma unroll
        for (int dt = 0; dt < 2; ++dt)
            #pragma unroll
            for (int r = 0; r < 4; ++r) {
                int i = w * 16 + 4 * lg + r;
                if (i < 49) {
                    long long o = (long long)h * SS + rowbase + (long long)i * 32 + dt * 16 + li;
                    float f = acc[dt][r];
                    ushort hh = bf16h(f);
                    oph[o] = hh;
                    opl[o] = bf16h(f - bf16f(hh));
                }
            }
    }
}

// ---------------------------------------------------------------------------
extern "C" void kernel_launch(void* const* d_in, const int* in_sizes, int n_in,
                              void* d_out, int out_size, void* d_ws, size_t ws_size,
                              hipStream_t stream)
{
    const float* x_sa      = (const float*)d_in[0];
    const float* x_ca      = (const float*)d_in[1];
    const float* lam_sa    = (const float*)d_in[2];
    const float* lam_ca    = (const float*)d_in[3];
    const float* sa_enh    = (const float*)d_in[4];
    const float* ca_enh    = (const float*)d_in[5];
    const float* W_sa_qkv  = (const float*)d_in[6];
    const float* b_sa_qkv  = (const float*)d_in[7];
    const float* W_sa_ct   = (const float*)d_in[8];
    const float* W_sa_cr   = (const float*)d_in[9];
    const float* W_ca_q    = (const float*)d_in[10];
    const float* b_ca_q    = (const float*)d_in[11];
    const float* W_ca_kv   = (const float*)d_in[12];
    const float* b_ca_kv   = (const float*)d_in[13];
    const float* W_ca_ct   = (const float*)d_in[14];
    const float* W_ca_cr   = (const float*)d_in[15];
    const float* rpb       = (const float*)d_in[16];
    const float* W_proj_sa = (const float*)d_in[17];
    const float* b_proj_sa = (const float*)d_in[18];
    const float* W_proj_ca = (const float*)d_in[19];
    const float* b_proj_ca = (const float*)d_in[20];
    float* out = (float*)d_out;
    float* ws  = (float*)d_ws;

    // ---- f32 combined-weight temps ----
    float* CW0 = ws;             // 192x576
    float* CW1 = CW0 + 110592;
    float* CW2 = CW1 + 110592;   // 192x192
    float* CW3 = CW2 + 36864;
    float* CW4 = CW3 + 36864;    // 192x384
    float* CW5 = CW4 + 73728;

    smallmm_kernel<<<108, 256, 0, stream>>>(W_sa_cr, W_sa_qkv, sa_enh, CW0, 576);
    smallmm_kernel<<<108, 256, 0, stream>>>(W_sa_ct, W_sa_qkv, sa_enh, CW1, 576);
    smallmm_kernel<<< 36, 256, 0, stream>>>(W_ca_cr, W_ca_q,   ca_enh, CW2, 192);
    smallmm_kernel<<< 36, 256, 0, stream>>>(W_ca_ct, W_ca_q,   ca_enh, CW3, 192);
    smallmm_kernel<<< 72, 256, 0, stream>>>(W_ca_cr, W_ca_kv,  ca_enh, CW4, 384);
    smallmm_kernel<<< 72, 256, 0, stream>>>(W_ca_ct, W_ca_kv,  ca_enh, CW5, 384);

    // ---- K-slabbed bf16 hi/lo weights ----
    ushort* wb = (ushort*)(ws + 442368);
    ushort* WsaqH = wb;                  ushort* WsaqL = WsaqH + 110592;
    ushort* C0H  = WsaqL + 110592;       ushort* C0L  = C0H + 110592;
    ushort* C1H  = C0L + 110592;         ushort* C1L  = C1H + 110592;
    ushort* WcqH = C1L + 110592;         ushort* WcqL = WcqH + 36864;
    ushort* C2H  = WcqL + 36864;         ushort* C2L  = C2H + 36864;
    ushort* C3H  = C2L + 36864;          ushort* C3L  = C3H + 36864;
    ushort* WckH = C3L + 36864;          ushort* WckL = WckH + 73728;
    ushort* C4H  = WckL + 73728;         ushort* C4L  = C4H + 73728;
    ushort* C5H  = C4L + 73728;          ushort* C5L  = C5H + 73728;
    ushort* WpsH = C5L + 73728;          ushort* WpsL = WpsH + 36864;
    ushort* WpcH = WpsL + 36864;         ushort* WpcL = WpcH + 36864;
    ushort* chunkU = WpcL + 36864;       // = wb + 1474560

    conv_wT<<<432, 256, 0, stream>>>(W_sa_qkv, 576, WsaqH, WsaqL);
    conv_wT<<<432, 256, 0, stream>>>(CW0,      576, C0H,  C0L);
    conv_wT<<<432, 256, 0, stream>>>(CW1,      576, C1H,  C1L);
    conv_wT<<<144, 256, 0, stream>>>(W_ca_q,   192, WcqH, WcqL);
    conv_wT<<<144, 256, 0, stream>>>(CW2,      192, C2H,  C2L);
    conv_wT<<<144, 256, 0, stream>>>(CW3,      192, C3H,  C3L);
    conv_wT<<<288, 256, 0, stream>>>(W_ca_kv,  384, WckH, WckL);
    conv_wT<<<288, 256, 0, stream>>>(CW4,      384, C4H,  C4L);
    conv_wT<<<288, 256, 0, stream>>>(CW5,      384, C5H,  C5L);
    conv_wT<<<144, 256, 0, stream>>>(W_proj_sa,192, WpsH, WpsL);
    conv_wT<<<144, 256, 0, stream>>>(W_proj_ca,192, WpcH, WpcL);

    // ---- chunking: 376320 bytes per batch element ----
    long long avail = (long long)ws_size - 442368LL * 4 - 1474560LL * 2;
    int cbmax = (int)(avail / 376320);
    if (cbmax > 2048) cbmax = 2048;
    if (cbmax < 1) cbmax = 1;

    const long long OUT1 = 2LL * 2048 * 49 * 192;
    dim3 blk(256);

    for (int c0 = 0; c0 < 2048; c0 += cbmax) {
        int cb = (c0 + cbmax <= 2048) ? cbmax : (2048 - c0);
        int M = cb * 49;
        long long SS = (long long)M * 32;
        int gy = (M + 127) / 128;
        int cblk = (int)(((long long)M * 24 + 255) / 256);
        if (cblk > 4096) cblk = 4096;

        // =========================== SA branch ===========================
        ushort* XtH = chunkU;                              // [6][M][32] each
        ushort* XtL = XtH + (long long)cbmax * 9408;
        ushort* XrH = XtL + (long long)cbmax * 9408;
        ushort* XrL = XrH + (long long)cbmax * 9408;
        ushort* QtH = XrL + (long long)cbmax * 9408;       // [18][M][32]
        ushort* QtL = QtH + (long long)cbmax * 28224;
        ushort* QrH = QtL + (long long)cbmax * 28224;
        ushort* QrL = QrH + (long long)cbmax * 28224;
        ushort* OtH = QrL + (long long)cbmax * 28224;      // [6][M][32]
        ushort* OtL = OtH + (long long)cbmax * 9408;
        ushort* OrH = OtL + (long long)cbmax * 9408;
        ushort* OrL = OrH + (long long)cbmax * 9408;

        conv_x<<<cblk, blk, 0, stream>>>(x_sa + (long long)c0 * 9408, 9408, XtH, XtL, M);
        conv_x<<<cblk, blk, 0, stream>>>(x_sa + (2048LL + c0) * 9408, 9408, XrH, XrL, M);

        dim3 g1(3, gy);
        gemm_slab<true, false><<<g1, blk, 0, stream>>>(
            XtH, XtL, XrH, XrL, WsaqH, WsaqL, C0H, C0L,
            b_sa_qkv, QtH, QtL, nullptr, 0, 576, M);
        gemm_slab<true, false><<<g1, blk, 0, stream>>>(
            XrH, XrL, XtH, XtL, WsaqH, WsaqL, C1H, C1L,
            b_sa_qkv, QrH, QrL, nullptr, 0, 576, M);

        attn_bf<<<cb * 6, blk, 0, stream>>>(
            QtH,           QtL,
            QtH + 6 * SS,  QtL + 6 * SS,
            QtH + 12 * SS, QtL + 12 * SS,
            QrH,           QrL,
            QrH + 6 * SS,  QrL + 6 * SS,
            QrH + 12 * SS, QrL + 12 * SS,
            SS, rpb, lam_sa, OtH, OtL, OrH, OrL);

        dim3 g2(1, gy);
        gemm_slab<false, true><<<g2, blk, 0, stream>>>(
            OtH, OtL, nullptr, nullptr, WpsH, WpsL, nullptr, nullptr,
            b_proj_sa, nullptr, nullptr, out + (long long)c0 * 9408, 9408, 192, M);
        gemm_slab<false, true><<<g2, blk, 0, stream>>>(
            OrH, OrL, nullptr, nullptr, WpsH, WpsL, nullptr, nullptr,
            b_proj_sa, nullptr, nullptr, out + (2048LL + c0) * 9408, 9408, 192, M);

        // =========================== CA branch ===========================
        ushort* CXtH = chunkU;                             // [6][M][32]
        ushort* CXtL = CXtH + (long long)cbmax * 9408;
        ushort* CXrH = CXtL + (long long)cbmax * 9408;
        ushort* CXrL = CXrH + (long long)cbmax * 9408;
        ushort* CQtH = CXrL + (long long)cbmax * 9408;     // [6][M][32]
        ushort* CQtL = CQtH + (long long)cbmax * 9408;
        ushort* CQrH = CQtL + (long long)cbmax * 9408;
        ushort* CQrL = CQrH + (long long)cbmax * 9408;
        ushort* KtH  = CQrL + (long long)cbmax * 9408;     // [12][M][32]
        ushort* KtL  = KtH + (long long)cbmax * 18816;
        ushort* KrH  = KtL + (long long)cbmax * 18816;
        ushort* KrL  = KrH + (long long)cbmax * 18816;
        ushort* COtH = KrL + (long long)cbmax * 18816;     // [6][M][32]
        ushort* COtL = COtH + (long long)cbmax * 9408;
        ushort* COrH = COtL + (long long)cbmax * 9408;
        ushort* COrL = COrH + (long long)cbmax * 9408;

        conv_x<<<cblk, blk, 0, stream>>>(x_ca + (long long)c0 * 18816, 18816, CXtH, CXtL, M);
        conv_x<<<cblk, blk, 0, stream>>>(x_ca + (long long)c0 * 18816 + 9408, 18816, CXrH, CXrL, M);

        gemm_slab<true, false><<<g2, blk, 0, stream>>>(
            CXtH, CXtL, CXrH, CXrL, WcqH, WcqL, C2H, C2L,
            b_ca_q, CQtH, CQtL, nullptr, 0, 192, M);
        gemm_slab<true, false><<<g2, blk, 0, stream>>>(
            CXrH, CXrL, CXtH, CXtL, WcqH, WcqL, C3H, C3L,
            b_ca_q, CQrH, CQrL, nullptr, 0, 192, M);

        dim3 g3(2, gy);
        gemm_slab<true, false><<<g3, blk, 0, stream>>>(
            CXtH, CXtL, CXrH, CXrL, WckH, WckL, C4H, C4L,
            b_ca_kv, KtH, KtL, nullptr, 0, 384, M);
        gemm_slab<true, false><<<g3, blk, 0, stream>>>(
            CXrH, CXrL, CXtH, CXtL, WckH, WckL, C5H, C5L,
            b_ca_kv, KrH, KrL, nullptr, 0, 384, M);

        attn_bf<<<cb * 6, blk, 0, stream>>>(
            CQtH,         CQtL,
            KtH,          KtL,
            KtH + 6 * SS, KtL + 6 * SS,
            CQrH,         CQrL,
            KrH,          KrL,
            KrH + 6 * SS, KrL + 6 * SS,
            SS, rpb, lam_ca, COtH, COtL, COrH, COrL);

        gemm_slab<false, true><<<g2, blk, 0, stream>>>(
            COtH, COtL, nullptr, nullptr, WpcH, WpcL, nullptr, nullptr,
            b_proj_ca, nullptr, nullptr,
            out + OUT1 + (long long)c0 * 18816, 18816, 192, M);
        gemm_slab<false, true><<<g2, blk, 0, stream>>>(
            COrH, COrL, nullptr, nullptr, WpcH, WpcL, nullptr, nullptr,
            b_proj_ca, nullptr, nullptr,
            out + OUT1 + (long long)c0 * 18816 + 9408, 18816, 192, M);
    }
}